// Round 11
// baseline (197.707 us; speedup 1.0000x reference)
//
#include <hip/hip_runtime.h>
#include <hip/hip_bf16.h>
#include <math.h>

// GCN link predictor, bf16 MFMA pipeline, counting-sort CSR build.
// R11: (1) gemm1 double-buffered with counted vmcnt(8) + raw s_barrier
// (T3+T4 2-phase); (2) dinv folded into h0 (hs = dinv*h0) so edge norm = w,
// enabling fused range_build (deg+dinv+offs+scatter in one kernel);
// (3) packed uint2 edge records everywhere.

#define NSL 256      // edge slices for bucketing passes
#define RSH 8        // log2(RANGE)
#define RNG 256      // nodes per range

typedef __attribute__((ext_vector_type(8))) short bf16x8;
typedef __attribute__((ext_vector_type(4))) float f32x4;

typedef const __attribute__((address_space(1))) unsigned int* gas_t;
typedef __attribute__((address_space(3))) unsigned int* las_t;

static __device__ __forceinline__ void gload_lds16(const void* g, void* l) {
    __builtin_amdgcn_global_load_lds((gas_t)g, (las_t)l, 16, 0, 0);
}

static __device__ __forceinline__ ushort f2b(float f) {
    __hip_bfloat16 h = __float2bfloat16(f);
    return *(ushort*)&h;
}
static __device__ __forceinline__ float b2f(ushort u) {
    unsigned int v = ((unsigned int)u) << 16;
    return *(float*)&v;
}
static __device__ __forceinline__ bf16x8 cvt8(float4 a, float4 b) {
    bf16x8 r;
    r[0] = (short)f2b(a.x); r[1] = (short)f2b(a.y); r[2] = (short)f2b(a.z); r[3] = (short)f2b(a.w);
    r[4] = (short)f2b(b.x); r[5] = (short)f2b(b.y); r[6] = (short)f2b(b.z); r[7] = (short)f2b(b.w);
    return r;
}

// ---------------- CSR build: counting sort by range ----------------

__global__ __launch_bounds__(256) void bucket_count(const int* __restrict__ dst,
                                                    int* __restrict__ cntA, int E, int NR) {
    __shared__ int lc[256];
    const int b = blockIdx.x, t = threadIdx.x;
    lc[t] = 0;
    __syncthreads();
    const int beg = (int)((long long)b * E / NSL);
    const int end = (int)((long long)(b + 1) * E / NSL);
    for (int e = beg + t; e < end; e += 256) atomicAdd(&lc[dst[e] >> RSH], 1);
    __syncthreads();
    if (t < NR) cntA[b * NR + t] = lc[t];
}

__global__ __launch_bounds__(256) void range_scan(int* __restrict__ cntA,
                                                  int* __restrict__ rtot, int NR) {
    __shared__ int s_[256];
    const int r = blockIdx.x, t = threadIdx.x;
    int v = cntA[t * NR + r];
    s_[t] = v;
    __syncthreads();
    for (int off = 1; off < 256; off <<= 1) {
        int add = (t >= off) ? s_[t - off] : 0;
        __syncthreads();
        s_[t] += add;
        __syncthreads();
    }
    cntA[t * NR + r] = s_[t] - v;
    if (t == 255) rtot[r] = s_[t];
}

__global__ __launch_bounds__(256) void base_scan(const int* __restrict__ rtot,
                                                 int* __restrict__ baseOut, int NR) {
    __shared__ int s_[256];
    const int t = threadIdx.x;
    int v = (t < NR) ? rtot[t] : 0;
    s_[t] = v;
    __syncthreads();
    for (int off = 1; off < 256; off <<= 1) {
        int add = (t >= off) ? s_[t - off] : 0;
        __syncthreads();
        s_[t] += add;
        __syncthreads();
    }
    if (t < NR) baseOut[t] = s_[t] - v;
    if (t == NR - 1) baseOut[NR] = s_[t];
}

// scatter edges into buckets as packed uint2 {(dstLocal<<24)|src, w_bits}
__global__ __launch_bounds__(256) void bucket_scatter(const int* __restrict__ src,
                                                      const int* __restrict__ dst,
                                                      const float* __restrict__ w,
                                                      const int* __restrict__ cntA,
                                                      const int* __restrict__ baseOut,
                                                      uint2* __restrict__ rec, int E, int NR) {
    __shared__ int cur[256];
    const int b = blockIdx.x, t = threadIdx.x;
    if (t < NR) cur[t] = cntA[b * NR + t] + baseOut[t];
    __syncthreads();
    const int beg = (int)((long long)b * E / NSL);
    const int end = (int)((long long)(b + 1) * E / NSL);
    for (int e = beg + t; e < end; e += 256) {
        int d = dst[e];
        int r = d >> RSH;
        int pos = atomicAdd(&cur[r], 1);
        rec[pos] = make_uint2(((unsigned int)(d & (RNG - 1)) << 24) | (unsigned int)src[e],
                              __float_as_uint(w[e]));
    }
}

// fused: per-range deg/dinv + offs (LDS scan) + CSR scatter (norm = w only)
__global__ __launch_bounds__(256) void range_build(const uint2* __restrict__ rec,
                                                   const int* __restrict__ baseOut,
                                                   float* __restrict__ dinv,
                                                   int* __restrict__ offs,
                                                   uint2* __restrict__ ce,
                                                   int N, int E) {
    __shared__ float lw[256];
    __shared__ int lc[256];
    __shared__ int sc[256];
    const int r = blockIdx.x, t = threadIdx.x;
    lw[t] = 0.f; lc[t] = 0;
    __syncthreads();
    const int beg = baseOut[r], end = baseOut[r + 1];
    for (int e = beg + t; e < end; e += 256) {
        uint2 pk = rec[e];
        int dl = pk.x >> 24;
        atomicAdd(&lc[dl], 1);
        atomicAdd(&lw[dl], __uint_as_float(pk.y));
    }
    __syncthreads();
    int v = lc[t];
    sc[t] = v;
    __syncthreads();
    for (int off = 1; off < 256; off <<= 1) {
        int add = (t >= off) ? sc[t - off] : 0;
        __syncthreads();
        sc[t] += add;
        __syncthreads();
    }
    const int node = (r << RSH) + t;
    const int o = beg + sc[t] - v;
    if (node < N) {
        dinv[node] = 1.0f / sqrtf(1.0f + lw[t]);   // self-loop weight 1
        offs[node] = o;
    }
    if (r == 0 && t == 0) offs[N] = E;
    lc[t] = o;                                     // reuse lc as cursor
    __syncthreads();
    for (int e = beg + t; e < end; e += 256) {
        uint2 pk = rec[e];
        int dl = pk.x >> 24;
        int pos = atomicAdd(&lc[dl], 1);
        ce[pos] = make_uint2(pk.x & 0xFFFFFF, pk.y);   // {src, w_bits}
    }
}

// ---------------- weight prep ----------------

__global__ __launch_bounds__(256) void tconv_kernel(const float* __restrict__ B,
                                                    ushort* __restrict__ BT, int K, int Nn) {
    int i = blockIdx.x * 256 + threadIdx.x;
    if (i < K * Nn) {
        int k = i / Nn, n = i % Nn;
        BT[(size_t)n * K + k] = f2b(B[i]);
    }
}

__global__ __launch_bounds__(256) void fold_kernel(const float* __restrict__ Wm,
                                                   const float* __restrict__ Wl,
                                                   const float* __restrict__ bm,
                                                   float* __restrict__ wmp,
                                                   float* __restrict__ wmq,
                                                   float* __restrict__ bpq) {
    int j = threadIdx.x;
    float sp = 0.f, sq = 0.f;
    for (int k = 0; k < 128; ++k) {
        float v = Wm[(size_t)j * 128 + k];
        sp += v * Wl[k];
        sq += v * Wl[128 + k];
    }
    wmp[j] = sp; wmq[j] = sq;
    if (j == 0) { float s = 0.f; for (int k = 0; k < 128; ++k) s += bm[k] * Wl[k];       bpq[0] = s; }
    if (j == 1) { float s = 0.f; for (int k = 0; k < 128; ++k) s += bm[k] * Wl[128 + k]; bpq[1] = s; }
}

// ---------------- GEMM1: hs = bf16(dinv * (x @ W1 + b1)) ----------------
// BM=64, BN=128(full), BK=64; 256 threads = 4 waves (2Mx2N), wave tile 32x64.
// Double-buffered global_load_lds staging with counted vmcnt(8) + raw barriers.
__global__ __launch_bounds__(256) void gemm1_mfma(const float* __restrict__ A,
                                                  const ushort* __restrict__ BT,  // [128][512]
                                                  const float* __restrict__ bias,
                                                  const float* __restrict__ dinv,
                                                  ushort* __restrict__ C, int M) {
    __shared__ float  As[2][64 * 64];     // fp32, 16 KB each
    __shared__ ushort Bs[2][128 * 64];    // bf16, 16 KB each
    const int t = threadIdx.x;
    const int bm = blockIdx.x * 64;
    const int lane = t & 63;
    const int wid = t >> 6;
    const int wm = (wid >> 1) * 32, wn = (wid & 1) * 64;

    f32x4 acc[2][4] = {};

    const int a_row_l = (lane >> 4);
    const int a_ib    = (lane & 15) * 16;
    const int b_row_l = (lane >> 3);
    const int b_ib    = (lane & 7) * 16;

    auto stage = [&](int buf, int k0) {
#pragma unroll
        for (int j = 0; j < 4; ++j) {
            int c = wid * 4 + j;
            int row = c * 4 + a_row_l;
            int sw = a_ib ^ ((row & 7) << 5);
            int grow = min(bm + row, M - 1);
            const char* src = (const char*)A + ((size_t)grow * 512 + k0) * 4 + sw;
            gload_lds16(src, (char*)As[buf] + c * 1024);
        }
#pragma unroll
        for (int j = 0; j < 4; ++j) {
            int c = wid * 4 + j;
            int row = c * 8 + b_row_l;
            int sw = b_ib ^ ((row & 7) << 4);
            const char* src = (const char*)BT + (size_t)row * 1024 + k0 * 2 + sw;
            gload_lds16(src, (char*)Bs[buf] + c * 1024);
        }
    };

    stage(0, 0);                               // 8 loads in flight
    int cur = 0;
#pragma unroll 1
    for (int tt = 0; tt < 8; ++tt) {
        if (tt < 7) {
            stage(cur ^ 1, (tt + 1) * 64);     // +8 loads (next tile)
            asm volatile("s_waitcnt vmcnt(8)" ::: "memory");   // current tile landed
        } else {
            asm volatile("s_waitcnt vmcnt(0)" ::: "memory");
        }
        __builtin_amdgcn_sched_barrier(0);
        __builtin_amdgcn_s_barrier();          // raw: no compiler vmcnt(0) drain
        const char* AsB = (const char*)As[cur];
        const char* BsB = (const char*)Bs[cur];
#pragma unroll
        for (int ks = 0; ks < 2; ++ks) {
            bf16x8 af[2], bfr[4];
#pragma unroll
            for (int mi = 0; mi < 2; ++mi) {
                int r = wm + mi * 16 + (lane & 15);
                int byte = r * 256 + ks * 128 + (lane >> 4) * 32;
                byte ^= (r & 7) << 5;
                float4 f0 = *(const float4*)(AsB + byte);
                float4 f1 = *(const float4*)(AsB + byte + 16);
                af[mi] = cvt8(f0, f1);
            }
#pragma unroll
            for (int ni = 0; ni < 4; ++ni) {
                int r = wn + ni * 16 + (lane & 15);
                int byte = r * 128 + ks * 64 + (lane >> 4) * 16;
                byte ^= (r & 7) << 4;
                bfr[ni] = *(const bf16x8*)(BsB + byte);
            }
#pragma unroll
            for (int mi = 0; mi < 2; ++mi)
#pragma unroll
                for (int ni = 0; ni < 4; ++ni)
                    acc[mi][ni] = __builtin_amdgcn_mfma_f32_16x16x32_bf16(af[mi], bfr[ni], acc[mi][ni], 0, 0, 0);
        }
        __builtin_amdgcn_s_barrier();          // all reads done before overwrite
        cur ^= 1;
    }

    // epilogue: (acc + bias) * dinv[row] -> bf16
#pragma unroll
    for (int mi = 0; mi < 2; ++mi)
#pragma unroll
        for (int r = 0; r < 4; ++r) {
            int row = bm + wm + mi * 16 + (lane >> 4) * 4 + r;
            if (row < M) {
                float dv = dinv[row];
#pragma unroll
                for (int ni = 0; ni < 4; ++ni) {
                    int col = wn + ni * 16 + (lane & 15);
                    C[(size_t)row * 128 + col] = f2b((acc[mi][ni][r] + bias[col]) * dv);
                }
            }
        }
}

// ---------------- aggregate: out = bf16(dinv[d]*(sum w*hs[s] + hs[d])), 8-wide MLP ----------------
__global__ __launch_bounds__(256) void aggregate_bf16(const ushort* __restrict__ hs,
                                                      const int* __restrict__ offs,
                                                      const uint2* __restrict__ ce,
                                                      const float* __restrict__ dinv,
                                                      ushort* __restrict__ out, int n) {
    int node = (int)((blockIdx.x * (size_t)blockDim.x + threadIdx.x) >> 6);
    int lane = threadIdx.x & 63;
    if (node >= n) return;
    unsigned int hv = *(const unsigned int*)(hs + (size_t)node * 128 + lane * 2);
    float ax = b2f((ushort)(hv & 0xffff));     // self term hs[d]
    float ay = b2f((ushort)(hv >> 16));
    int beg = offs[node], end = offs[node + 1];
    for (int e = beg; e < end; e += 8) {
        uint2 rr[8];
#pragma unroll
        for (int j = 0; j < 8; ++j) {
            bool v = (e + j) < end;
            rr[j] = v ? ce[e + j] : make_uint2((unsigned)node, 0u);
        }
        unsigned int vv[8];
#pragma unroll
        for (int j = 0; j < 8; ++j)
            vv[j] = *(const unsigned int*)(hs + (size_t)rr[j].x * 128 + lane * 2);
#pragma unroll
        for (int j = 0; j < 8; ++j) {
            float wj = __uint_as_float(rr[j].y);
            ax += wj * b2f((ushort)(vv[j] & 0xffff));
            ay += wj * b2f((ushort)(vv[j] >> 16));
        }
    }
    float dv = dinv[node];
    unsigned int o = (unsigned int)f2b(ax * dv) | ((unsigned int)f2b(ay * dv) << 16);
    *(unsigned int*)(out + (size_t)node * 128 + lane * 2) = o;
}

// ---------------- GEMM2 fused: pes,qes = dinv * (relu(agg1@Wc + bc) @ [wmp,wmq]) ----------------
__global__ __launch_bounds__(64) void gemm2_stream(const ushort* __restrict__ A,   // [M][128] bf16
                                                   const ushort* __restrict__ BT,  // [256][128] bf16
                                                   const float* __restrict__ bc,
                                                   const float* __restrict__ wmp,
                                                   const float* __restrict__ wmq,
                                                   const float* __restrict__ dinv,
                                                   float* __restrict__ pe,
                                                   float* __restrict__ qe, int M) {
    const int lane = threadIdx.x;
    const int r0 = blockIdx.x * 16;
    const int lrow = lane & 15;
    const int lk   = (lane >> 4) * 8;

    f32x4 acc[16] = {};

    const ushort* a  = A  + (size_t)min(r0 + lrow, M - 1) * 128 + lk;
    const ushort* bp = BT + (size_t)lrow * 128 + lk;

#pragma unroll
    for (int ks = 0; ks < 4; ++ks) {
        const int k0 = ks * 32;
        bf16x8 af = *(const bf16x8*)(a + k0);
#pragma unroll
        for (int ni = 0; ni < 16; ++ni) {
            bf16x8 bfr = *(const bf16x8*)(bp + (size_t)ni * 16 * 128 + k0);
            acc[ni] = __builtin_amdgcn_mfma_f32_16x16x32_bf16(af, bfr, acc[ni], 0, 0, 0);
        }
    }

    float bcv[16], wpv[16], wqv[16];
#pragma unroll
    for (int ni = 0; ni < 16; ++ni) {
        int col = ni * 16 + lrow;
        bcv[ni] = bc[col];
        wpv[ni] = wmp[col];
        wqv[ni] = wmq[col];
    }
#pragma unroll
    for (int r = 0; r < 4; ++r) {
        float sp = 0.f, sq = 0.f;
#pragma unroll
        for (int ni = 0; ni < 16; ++ni) {
            float h = fmaxf(acc[ni][r] + bcv[ni], 0.f);
            sp += h * wpv[ni];
            sq += h * wqv[ni];
        }
#pragma unroll
        for (int off = 1; off < 16; off <<= 1) {
            sp += __shfl_xor(sp, off);
            sq += __shfl_xor(sq, off);
        }
        if (lrow == 0) {
            int row = r0 + (lane >> 4) * 4 + r;
            if (row < M) {
                float dv = dinv[row];
                pe[row] = sp * dv;
                qe[row] = sq * dv;
            }
        }
    }
}

// ---------------- scalar aggregation: p = dinv*(sum w*pes[s] + pes[i]) + bpq ----------------
__global__ __launch_bounds__(256) void agg_scalar(const float* __restrict__ pe,
                                                  const float* __restrict__ qe,
                                                  const int* __restrict__ offs,
                                                  const uint2* __restrict__ ce,
                                                  const float* __restrict__ dinv,
                                                  const float* __restrict__ bpq,
                                                  float* __restrict__ p,
                                                  float* __restrict__ q, int n) {
    int i = blockIdx.x * 256 + threadIdx.x;
    if (i >= n) return;
    float ap = pe[i], aq = qe[i];
    int beg = offs[i], end = offs[i + 1];
    for (int k = beg; k < end; k += 4) {
        uint2 rr[4];
#pragma unroll
        for (int j = 0; j < 4; ++j) {
            bool v = (k + j) < end;
            rr[j] = v ? ce[k + j] : make_uint2((unsigned)i, 0u);
        }
        float pv[4], qv[4];
#pragma unroll
        for (int j = 0; j < 4; ++j) { pv[j] = pe[rr[j].x]; qv[j] = qe[rr[j].x]; }
#pragma unroll
        for (int j = 0; j < 4; ++j) {
            float wj = __uint_as_float(rr[j].y);
            ap += wj * pv[j];
            aq += wj * qv[j];
        }
    }
    float dv = dinv[i];
    p[i] = ap * dv + bpq[0];
    q[i] = aq * dv + bpq[1];
}

__global__ __launch_bounds__(256) void edge_out_kernel(const int* __restrict__ src,
                                                       const int* __restrict__ dst,
                                                       const float* __restrict__ p,
                                                       const float* __restrict__ q,
                                                       const float* __restrict__ bl,
                                                       float* __restrict__ out, int e) {
    int i = blockIdx.x * 256 + threadIdx.x;
    if (i < e) {
        float t = p[src[i]] + q[dst[i]] + bl[0];
        out[i] = 1.0f / (1.0f + expf(-t));
    }
}

// ---------------- launch ----------------

extern "C" void kernel_launch(void* const* d_in, const int* in_sizes, int n_in,
                              void* d_out, int out_size, void* d_ws, size_t ws_size,
                              hipStream_t stream) {
    const int*   edge_index = (const int*)d_in[0];
    const float* x   = (const float*)d_in[1];
    const float* w   = (const float*)d_in[2];
    const float* W1  = (const float*)d_in[3];
    const float* b1  = (const float*)d_in[4];
    const float* Wc  = (const float*)d_in[5];
    const float* bc  = (const float*)d_in[6];
    const float* Wm  = (const float*)d_in[7];
    const float* bm  = (const float*)d_in[8];
    const float* Wl  = (const float*)d_in[9];
    const float* bl  = (const float*)d_in[10];
    float* out = (float*)d_out;

    const int E  = in_sizes[2];            // 800000
    const int H  = in_sizes[4];            // 128
    const int F  = in_sizes[3] / H;        // 512
    const int N  = in_sizes[1] / F;        // 50000
    const int H2 = 2 * H;                  // 256
    const int NR = (N + RNG - 1) / RNG;    // 196 ranges (<= 256)

    const int* src = edge_index;
    const int* dst = edge_index + E;

    char* ws = (char*)d_ws;
    size_t off = 0;
    auto alloc = [&](size_t bytes) -> void* {
        off = (off + 255) & ~(size_t)255;
        void* r = ws + off;
        off += bytes;
        return r;
    };
    int*    cntA    = (int*)   alloc((size_t)NSL * NR * 4);
    int*    rtot    = (int*)   alloc((size_t)NR * 4);
    int*    baseOut = (int*)   alloc((size_t)(NR + 1) * 4);
    uint2*  rec     = (uint2*) alloc((size_t)E * 8);
    uint2*  ce      = (uint2*) alloc((size_t)E * 8);
    float*  dinv    = (float*) alloc((size_t)N * 4);
    int*    offs    = (int*)   alloc((size_t)(N + 1) * 4);
    ushort* hs_bf   = (ushort*)alloc((size_t)N * H * 2);
    ushort* agg1_bf = (ushort*)alloc((size_t)N * H * 2);
    ushort* W1T     = (ushort*)alloc((size_t)H * F * 2);
    ushort* WcT     = (ushort*)alloc((size_t)H2 * H * 2);
    float*  wmp     = (float*) alloc(H2 * 4);
    float*  wmq     = (float*) alloc(H2 * 4);
    float*  bpq     = (float*) alloc(2 * 4);
    float*  pe      = (float*) alloc((size_t)N * 4);
    float*  qe      = (float*) alloc((size_t)N * 4);
    float*  p       = (float*) alloc((size_t)N * 4);
    float*  q       = (float*) alloc((size_t)N * 4);
    (void)ws_size; (void)n_in; (void)out_size;

    int nbN  = (N + 255) / 256;
    int nbE  = (E + 255) / 256;
    int nbW  = (int)(((size_t)N * 64 + 255) / 256);
    int nb64 = (N + 63) / 64;
    int nb16 = (N + 15) / 16;

    // CSR build
    bucket_count<<<NSL, 256, 0, stream>>>(dst, cntA, E, NR);
    range_scan<<<NR, 256, 0, stream>>>(cntA, rtot, NR);
    base_scan<<<1, 256, 0, stream>>>(rtot, baseOut, NR);
    bucket_scatter<<<NSL, 256, 0, stream>>>(src, dst, w, cntA, baseOut, rec, E, NR);
    range_build<<<NR, 256, 0, stream>>>(rec, baseOut, dinv, offs, ce, N, E);

    // weight prep
    tconv_kernel<<<(F * H + 255) / 256, 256, 0, stream>>>(W1, W1T, F, H);
    tconv_kernel<<<(H * H2 + 255) / 256, 256, 0, stream>>>(Wc, WcT, H, H2);
    fold_kernel<<<1, 256, 0, stream>>>(Wm, Wl, bm, wmp, wmq, bpq);

    // hs = bf16(dinv * (x @ W1 + b1))
    gemm1_mfma<<<nb64, 256, 0, stream>>>(x, W1T, b1, dinv, hs_bf, N);
    // agg1 = bf16(dinv * (sum w*hs[s] + hs))
    aggregate_bf16<<<nbW, 256, 0, stream>>>(hs_bf, offs, ce, dinv, agg1_bf, N);
    // pes,qes = dinv * (relu(agg1@Wc + bc) @ [wmp,wmq])
    gemm2_stream<<<nb16, 64, 0, stream>>>(agg1_bf, WcT, bc, wmp, wmq, dinv, pe, qe, N);
    // p,q
    agg_scalar<<<nbN, 256, 0, stream>>>(pe, qe, offs, ce, dinv, bpq, p, q, N);
    // out
    edge_out_kernel<<<nbE, 256, 0, stream>>>(src, dst, p, q, bl, out, E);
}

// Round 12
// 189.967 us; speedup vs baseline: 1.0407x; 1.0407x over previous
//
#include <hip/hip_runtime.h>
#include <hip/hip_bf16.h>
#include <math.h>

// GCN link predictor, bf16 MFMA pipeline, counting-sort CSR build.
// R12: gemm1 reverted to R10's measured-best single-buffered global_load_lds
// structure (R11's 64KB dbuf halved occupancy: -20us). Keeps R11's CSR
// improvements (fused range_build, norm=w via dinv-folded hs, uint2 records)
// and fuses the 3 weight-prep launches into one kernel.

#define NSL 256      // edge slices for bucketing passes
#define RSH 8        // log2(RANGE)
#define RNG 256      // nodes per range

typedef __attribute__((ext_vector_type(8))) short bf16x8;
typedef __attribute__((ext_vector_type(4))) float f32x4;

typedef const __attribute__((address_space(1))) unsigned int* gas_t;
typedef __attribute__((address_space(3))) unsigned int* las_t;

static __device__ __forceinline__ void gload_lds16(const void* g, void* l) {
    __builtin_amdgcn_global_load_lds((gas_t)g, (las_t)l, 16, 0, 0);
}

static __device__ __forceinline__ ushort f2b(float f) {
    __hip_bfloat16 h = __float2bfloat16(f);
    return *(ushort*)&h;
}
static __device__ __forceinline__ float b2f(ushort u) {
    unsigned int v = ((unsigned int)u) << 16;
    return *(float*)&v;
}
static __device__ __forceinline__ bf16x8 cvt8(float4 a, float4 b) {
    bf16x8 r;
    r[0] = (short)f2b(a.x); r[1] = (short)f2b(a.y); r[2] = (short)f2b(a.z); r[3] = (short)f2b(a.w);
    r[4] = (short)f2b(b.x); r[5] = (short)f2b(b.y); r[6] = (short)f2b(b.z); r[7] = (short)f2b(b.w);
    return r;
}

// ---------------- CSR build: counting sort by range ----------------

__global__ __launch_bounds__(256) void bucket_count(const int* __restrict__ dst,
                                                    int* __restrict__ cntA, int E, int NR) {
    __shared__ int lc[256];
    const int b = blockIdx.x, t = threadIdx.x;
    lc[t] = 0;
    __syncthreads();
    const int beg = (int)((long long)b * E / NSL);
    const int end = (int)((long long)(b + 1) * E / NSL);
    for (int e = beg + t; e < end; e += 256) atomicAdd(&lc[dst[e] >> RSH], 1);
    __syncthreads();
    if (t < NR) cntA[b * NR + t] = lc[t];
}

__global__ __launch_bounds__(256) void range_scan(int* __restrict__ cntA,
                                                  int* __restrict__ rtot, int NR) {
    __shared__ int s_[256];
    const int r = blockIdx.x, t = threadIdx.x;
    int v = cntA[t * NR + r];
    s_[t] = v;
    __syncthreads();
    for (int off = 1; off < 256; off <<= 1) {
        int add = (t >= off) ? s_[t - off] : 0;
        __syncthreads();
        s_[t] += add;
        __syncthreads();
    }
    cntA[t * NR + r] = s_[t] - v;
    if (t == 255) rtot[r] = s_[t];
}

__global__ __launch_bounds__(256) void base_scan(const int* __restrict__ rtot,
                                                 int* __restrict__ baseOut, int NR) {
    __shared__ int s_[256];
    const int t = threadIdx.x;
    int v = (t < NR) ? rtot[t] : 0;
    s_[t] = v;
    __syncthreads();
    for (int off = 1; off < 256; off <<= 1) {
        int add = (t >= off) ? s_[t - off] : 0;
        __syncthreads();
        s_[t] += add;
        __syncthreads();
    }
    if (t < NR) baseOut[t] = s_[t] - v;
    if (t == NR - 1) baseOut[NR] = s_[t];
}

// scatter edges into buckets as packed uint2 {(dstLocal<<24)|src, w_bits}
__global__ __launch_bounds__(256) void bucket_scatter(const int* __restrict__ src,
                                                      const int* __restrict__ dst,
                                                      const float* __restrict__ w,
                                                      const int* __restrict__ cntA,
                                                      const int* __restrict__ baseOut,
                                                      uint2* __restrict__ rec, int E, int NR) {
    __shared__ int cur[256];
    const int b = blockIdx.x, t = threadIdx.x;
    if (t < NR) cur[t] = cntA[b * NR + t] + baseOut[t];
    __syncthreads();
    const int beg = (int)((long long)b * E / NSL);
    const int end = (int)((long long)(b + 1) * E / NSL);
    for (int e = beg + t; e < end; e += 256) {
        int d = dst[e];
        int r = d >> RSH;
        int pos = atomicAdd(&cur[r], 1);
        rec[pos] = make_uint2(((unsigned int)(d & (RNG - 1)) << 24) | (unsigned int)src[e],
                              __float_as_uint(w[e]));
    }
}

// fused: per-range deg/dinv + offs (LDS scan) + CSR scatter (norm = w only)
__global__ __launch_bounds__(256) void range_build(const uint2* __restrict__ rec,
                                                   const int* __restrict__ baseOut,
                                                   float* __restrict__ dinv,
                                                   int* __restrict__ offs,
                                                   uint2* __restrict__ ce,
                                                   int N, int E) {
    __shared__ float lw[256];
    __shared__ int lc[256];
    __shared__ int sc[256];
    const int r = blockIdx.x, t = threadIdx.x;
    lw[t] = 0.f; lc[t] = 0;
    __syncthreads();
    const int beg = baseOut[r], end = baseOut[r + 1];
    for (int e = beg + t; e < end; e += 256) {
        uint2 pk = rec[e];
        int dl = pk.x >> 24;
        atomicAdd(&lc[dl], 1);
        atomicAdd(&lw[dl], __uint_as_float(pk.y));
    }
    __syncthreads();
    int v = lc[t];
    sc[t] = v;
    __syncthreads();
    for (int off = 1; off < 256; off <<= 1) {
        int add = (t >= off) ? sc[t - off] : 0;
        __syncthreads();
        sc[t] += add;
        __syncthreads();
    }
    const int node = (r << RSH) + t;
    const int o = beg + sc[t] - v;
    if (node < N) {
        dinv[node] = 1.0f / sqrtf(1.0f + lw[t]);   // self-loop weight 1
        offs[node] = o;
    }
    if (r == 0 && t == 0) offs[N] = E;
    lc[t] = o;                                     // reuse lc as cursor
    __syncthreads();
    for (int e = beg + t; e < end; e += 256) {
        uint2 pk = rec[e];
        int dl = pk.x >> 24;
        int pos = atomicAdd(&lc[dl], 1);
        ce[pos] = make_uint2(pk.x & 0xFFFFFF, pk.y);   // {src, w_bits}
    }
}

// ---------------- weight prep (fused: tconv W1 + tconv Wc + fold) ----------------
__global__ __launch_bounds__(256) void prep_kernel(const float* __restrict__ W1,
                                                   const float* __restrict__ Wc,
                                                   const float* __restrict__ Wm,
                                                   const float* __restrict__ Wl,
                                                   const float* __restrict__ bm,
                                                   ushort* __restrict__ W1T,
                                                   ushort* __restrict__ WcT,
                                                   float* __restrict__ wmp,
                                                   float* __restrict__ wmq,
                                                   float* __restrict__ bpq,
                                                   int F, int H, int H2,
                                                   int nb1, int nb2) {
    const int b = blockIdx.x, t = threadIdx.x;
    if (b < nb1) {
        int i = b * 256 + t;
        if (i < F * H) {
            int k = i / H, n = i % H;
            W1T[(size_t)n * F + k] = f2b(W1[i]);
        }
    } else if (b < nb1 + nb2) {
        int i = (b - nb1) * 256 + t;
        if (i < H * H2) {
            int k = i / H2, n = i % H2;
            WcT[(size_t)n * H + k] = f2b(Wc[i]);
        }
    } else {
        int j = t;   // 0..255 == H2
        float sp = 0.f, sq = 0.f;
        for (int k = 0; k < 128; ++k) {
            float v = Wm[(size_t)j * 128 + k];
            sp += v * Wl[k];
            sq += v * Wl[128 + k];
        }
        wmp[j] = sp; wmq[j] = sq;
        if (j == 0) { float s = 0.f; for (int k = 0; k < 128; ++k) s += bm[k] * Wl[k];       bpq[0] = s; }
        if (j == 1) { float s = 0.f; for (int k = 0; k < 128; ++k) s += bm[k] * Wl[128 + k]; bpq[1] = s; }
    }
}

// ---------------- GEMM1: hs = bf16(dinv * (x @ W1 + b1)), m97/R10 structure ----------------
// BM=64, BN=128(full), BK=64; 256 threads = 4 waves (2Mx2N), wave tile 32x64.
// Single-buffered LDS (32 KB), global_load_lds width-16 staging, 2 barriers/K-step.
__global__ __launch_bounds__(256) void gemm1_mfma(const float* __restrict__ A,
                                                  const ushort* __restrict__ BT,  // [128][512]
                                                  const float* __restrict__ bias,
                                                  const float* __restrict__ dinv,
                                                  ushort* __restrict__ C, int M) {
    __shared__ float  As[64 * 64];     // fp32, 16 KB; row stride 256 B
    __shared__ ushort Bs[128 * 64];    // bf16, 16 KB; row stride 128 B
    char* AsB = (char*)As;
    char* BsB = (char*)Bs;
    const int t = threadIdx.x;
    const int bm = blockIdx.x * 64;
    const int lane = t & 63;
    const int wid = t >> 6;
    const int wm = (wid >> 1) * 32, wn = (wid & 1) * 64;

    f32x4 acc[2][4] = {};

    const int a_row_l = (lane >> 4);
    const int a_ib    = (lane & 15) * 16;
    const int b_row_l = (lane >> 3);
    const int b_ib    = (lane & 7) * 16;

#pragma unroll 1
    for (int tt = 0; tt < 8; ++tt) {
        const int k0 = tt * 64;
        // stage A (pre-swizzled source cols; LDS linear)
#pragma unroll
        for (int j = 0; j < 4; ++j) {
            int c = wid * 4 + j;
            int row = c * 4 + a_row_l;
            int sw = a_ib ^ ((row & 7) << 5);
            int grow = min(bm + row, M - 1);
            const char* src = (const char*)A + ((size_t)grow * 512 + k0) * 4 + sw;
            gload_lds16(src, AsB + c * 1024);
        }
        // stage B
#pragma unroll
        for (int j = 0; j < 4; ++j) {
            int c = wid * 4 + j;
            int row = c * 8 + b_row_l;
            int sw = b_ib ^ ((row & 7) << 4);
            const char* src = (const char*)BT + (size_t)row * 1024 + k0 * 2 + sw;
            gload_lds16(src, BsB + c * 1024);
        }
        __syncthreads();   // drain DMA -> tile ready
#pragma unroll
        for (int ks = 0; ks < 2; ++ks) {
            bf16x8 af[2], bfr[4];
#pragma unroll
            for (int mi = 0; mi < 2; ++mi) {
                int r = wm + mi * 16 + (lane & 15);
                int byte = r * 256 + ks * 128 + (lane >> 4) * 32;
                byte ^= (r & 7) << 5;
                float4 f0 = *(const float4*)(AsB + byte);
                float4 f1 = *(const float4*)(AsB + byte + 16);
                af[mi] = cvt8(f0, f1);
            }
#pragma unroll
            for (int ni = 0; ni < 4; ++ni) {
                int r = wn + ni * 16 + (lane & 15);
                int byte = r * 128 + ks * 64 + (lane >> 4) * 16;
                byte ^= (r & 7) << 4;
                bfr[ni] = *(const bf16x8*)(BsB + byte);
            }
#pragma unroll
            for (int mi = 0; mi < 2; ++mi)
#pragma unroll
                for (int ni = 0; ni < 4; ++ni)
                    acc[mi][ni] = __builtin_amdgcn_mfma_f32_16x16x32_bf16(af[mi], bfr[ni], acc[mi][ni], 0, 0, 0);
        }
        __syncthreads();   // protect LDS for next tile
    }

    // epilogue: (acc + bias) * dinv[row] -> bf16
#pragma unroll
    for (int mi = 0; mi < 2; ++mi)
#pragma unroll
        for (int r = 0; r < 4; ++r) {
            int row = bm + wm + mi * 16 + (lane >> 4) * 4 + r;
            if (row < M) {
                float dv = dinv[row];
#pragma unroll
                for (int ni = 0; ni < 4; ++ni) {
                    int col = wn + ni * 16 + (lane & 15);
                    C[(size_t)row * 128 + col] = f2b((acc[mi][ni][r] + bias[col]) * dv);
                }
            }
        }
}

// ---------------- aggregate: out = bf16(dinv[d]*(sum w*hs[s] + hs[d])), 8-wide MLP ----------------
__global__ __launch_bounds__(256) void aggregate_bf16(const ushort* __restrict__ hs,
                                                      const int* __restrict__ offs,
                                                      const uint2* __restrict__ ce,
                                                      const float* __restrict__ dinv,
                                                      ushort* __restrict__ out, int n) {
    int node = (int)((blockIdx.x * (size_t)blockDim.x + threadIdx.x) >> 6);
    int lane = threadIdx.x & 63;
    if (node >= n) return;
    unsigned int hv = *(const unsigned int*)(hs + (size_t)node * 128 + lane * 2);
    float ax = b2f((ushort)(hv & 0xffff));     // self term hs[d]
    float ay = b2f((ushort)(hv >> 16));
    int beg = offs[node], end = offs[node + 1];
    for (int e = beg; e < end; e += 8) {
        uint2 rr[8];
#pragma unroll
        for (int j = 0; j < 8; ++j) {
            bool v = (e + j) < end;
            rr[j] = v ? ce[e + j] : make_uint2((unsigned)node, 0u);
        }
        unsigned int vv[8];
#pragma unroll
        for (int j = 0; j < 8; ++j)
            vv[j] = *(const unsigned int*)(hs + (size_t)rr[j].x * 128 + lane * 2);
#pragma unroll
        for (int j = 0; j < 8; ++j) {
            float wj = __uint_as_float(rr[j].y);
            ax += wj * b2f((ushort)(vv[j] & 0xffff));
            ay += wj * b2f((ushort)(vv[j] >> 16));
        }
    }
    float dv = dinv[node];
    unsigned int o = (unsigned int)f2b(ax * dv) | ((unsigned int)f2b(ay * dv) << 16);
    *(unsigned int*)(out + (size_t)node * 128 + lane * 2) = o;
}

// ---------------- GEMM2 fused: pes,qes = dinv * (relu(agg1@Wc + bc) @ [wmp,wmq]) ----------------
__global__ __launch_bounds__(64) void gemm2_stream(const ushort* __restrict__ A,   // [M][128] bf16
                                                   const ushort* __restrict__ BT,  // [256][128] bf16
                                                   const float* __restrict__ bc,
                                                   const float* __restrict__ wmp,
                                                   const float* __restrict__ wmq,
                                                   const float* __restrict__ dinv,
                                                   float* __restrict__ pe,
                                                   float* __restrict__ qe, int M) {
    const int lane = threadIdx.x;
    const int r0 = blockIdx.x * 16;
    const int lrow = lane & 15;
    const int lk   = (lane >> 4) * 8;

    f32x4 acc[16] = {};

    const ushort* a  = A  + (size_t)min(r0 + lrow, M - 1) * 128 + lk;
    const ushort* bp = BT + (size_t)lrow * 128 + lk;

#pragma unroll
    for (int ks = 0; ks < 4; ++ks) {
        const int k0 = ks * 32;
        bf16x8 af = *(const bf16x8*)(a + k0);
#pragma unroll
        for (int ni = 0; ni < 16; ++ni) {
            bf16x8 bfr = *(const bf16x8*)(bp + (size_t)ni * 16 * 128 + k0);
            acc[ni] = __builtin_amdgcn_mfma_f32_16x16x32_bf16(af, bfr, acc[ni], 0, 0, 0);
        }
    }

    float bcv[16], wpv[16], wqv[16];
#pragma unroll
    for (int ni = 0; ni < 16; ++ni) {
        int col = ni * 16 + lrow;
        bcv[ni] = bc[col];
        wpv[ni] = wmp[col];
        wqv[ni] = wmq[col];
    }
#pragma unroll
    for (int r = 0; r < 4; ++r) {
        float sp = 0.f, sq = 0.f;
#pragma unroll
        for (int ni = 0; ni < 16; ++ni) {
            float h = fmaxf(acc[ni][r] + bcv[ni], 0.f);
            sp += h * wpv[ni];
            sq += h * wqv[ni];
        }
#pragma unroll
        for (int off = 1; off < 16; off <<= 1) {
            sp += __shfl_xor(sp, off);
            sq += __shfl_xor(sq, off);
        }
        if (lrow == 0) {
            int row = r0 + (lane >> 4) * 4 + r;
            if (row < M) {
                float dv = dinv[row];
                pe[row] = sp * dv;
                qe[row] = sq * dv;
            }
        }
    }
}

// ---------------- scalar aggregation: p = dinv*(sum w*pes[s] + pes[i]) + bpq ----------------
__global__ __launch_bounds__(256) void agg_scalar(const float* __restrict__ pe,
                                                  const float* __restrict__ qe,
                                                  const int* __restrict__ offs,
                                                  const uint2* __restrict__ ce,
                                                  const float* __restrict__ dinv,
                                                  const float* __restrict__ bpq,
                                                  float* __restrict__ p,
                                                  float* __restrict__ q, int n) {
    int i = blockIdx.x * 256 + threadIdx.x;
    if (i >= n) return;
    float ap = pe[i], aq = qe[i];
    int beg = offs[i], end = offs[i + 1];
    for (int k = beg; k < end; k += 4) {
        uint2 rr[4];
#pragma unroll
        for (int j = 0; j < 4; ++j) {
            bool v = (k + j) < end;
            rr[j] = v ? ce[k + j] : make_uint2((unsigned)i, 0u);
        }
        float pv[4], qv[4];
#pragma unroll
        for (int j = 0; j < 4; ++j) { pv[j] = pe[rr[j].x]; qv[j] = qe[rr[j].x]; }
#pragma unroll
        for (int j = 0; j < 4; ++j) {
            float wj = __uint_as_float(rr[j].y);
            ap += wj * pv[j];
            aq += wj * qv[j];
        }
    }
    float dv = dinv[i];
    p[i] = ap * dv + bpq[0];
    q[i] = aq * dv + bpq[1];
}

__global__ __launch_bounds__(256) void edge_out_kernel(const int* __restrict__ src,
                                                       const int* __restrict__ dst,
                                                       const float* __restrict__ p,
                                                       const float* __restrict__ q,
                                                       const float* __restrict__ bl,
                                                       float* __restrict__ out, int e) {
    int i = blockIdx.x * 256 + threadIdx.x;
    if (i < e) {
        float t = p[src[i]] + q[dst[i]] + bl[0];
        out[i] = 1.0f / (1.0f + expf(-t));
    }
}

// ---------------- launch ----------------

extern "C" void kernel_launch(void* const* d_in, const int* in_sizes, int n_in,
                              void* d_out, int out_size, void* d_ws, size_t ws_size,
                              hipStream_t stream) {
    const int*   edge_index = (const int*)d_in[0];
    const float* x   = (const float*)d_in[1];
    const float* w   = (const float*)d_in[2];
    const float* W1  = (const float*)d_in[3];
    const float* b1  = (const float*)d_in[4];
    const float* Wc  = (const float*)d_in[5];
    const float* bc  = (const float*)d_in[6];
    const float* Wm  = (const float*)d_in[7];
    const float* bm  = (const float*)d_in[8];
    const float* Wl  = (const float*)d_in[9];
    const float* bl  = (const float*)d_in[10];
    float* out = (float*)d_out;

    const int E  = in_sizes[2];            // 800000
    const int H  = in_sizes[4];            // 128
    const int F  = in_sizes[3] / H;        // 512
    const int N  = in_sizes[1] / F;        // 50000
    const int H2 = 2 * H;                  // 256
    const int NR = (N + RNG - 1) / RNG;    // 196 ranges (<= 256)

    const int* src = edge_index;
    const int* dst = edge_index + E;

    char* ws = (char*)d_ws;
    size_t off = 0;
    auto alloc = [&](size_t bytes) -> void* {
        off = (off + 255) & ~(size_t)255;
        void* r = ws + off;
        off += bytes;
        return r;
    };
    int*    cntA    = (int*)   alloc((size_t)NSL * NR * 4);
    int*    rtot    = (int*)   alloc((size_t)NR * 4);
    int*    baseOut = (int*)   alloc((size_t)(NR + 1) * 4);
    uint2*  rec     = (uint2*) alloc((size_t)E * 8);
    uint2*  ce      = (uint2*) alloc((size_t)E * 8);
    float*  dinv    = (float*) alloc((size_t)N * 4);
    int*    offs    = (int*)   alloc((size_t)(N + 1) * 4);
    ushort* hs_bf   = (ushort*)alloc((size_t)N * H * 2);
    ushort* agg1_bf = (ushort*)alloc((size_t)N * H * 2);
    ushort* W1T     = (ushort*)alloc((size_t)H * F * 2);
    ushort* WcT     = (ushort*)alloc((size_t)H2 * H * 2);
    float*  wmp     = (float*) alloc(H2 * 4);
    float*  wmq     = (float*) alloc(H2 * 4);
    float*  bpq     = (float*) alloc(2 * 4);
    float*  pe      = (float*) alloc((size_t)N * 4);
    float*  qe      = (float*) alloc((size_t)N * 4);
    float*  p       = (float*) alloc((size_t)N * 4);
    float*  q       = (float*) alloc((size_t)N * 4);
    (void)ws_size; (void)n_in; (void)out_size;

    int nbN  = (N + 255) / 256;
    int nbE  = (E + 255) / 256;
    int nbW  = (int)(((size_t)N * 64 + 255) / 256);
    int nb64 = (N + 63) / 64;
    int nb16 = (N + 15) / 16;
    int nb1  = (F * H + 255) / 256;     // 256
    int nb2  = (H * H2 + 255) / 256;    // 128

    // CSR build
    bucket_count<<<NSL, 256, 0, stream>>>(dst, cntA, E, NR);
    range_scan<<<NR, 256, 0, stream>>>(cntA, rtot, NR);
    base_scan<<<1, 256, 0, stream>>>(rtot, baseOut, NR);
    bucket_scatter<<<NSL, 256, 0, stream>>>(src, dst, w, cntA, baseOut, rec, E, NR);
    range_build<<<NR, 256, 0, stream>>>(rec, baseOut, dinv, offs, ce, N, E);

    // weight prep (fused)
    prep_kernel<<<nb1 + nb2 + 1, 256, 0, stream>>>(W1, Wc, Wm, Wl, bm, W1T, WcT,
                                                   wmp, wmq, bpq, F, H, H2, nb1, nb2);

    // hs = bf16(dinv * (x @ W1 + b1))
    gemm1_mfma<<<nb64, 256, 0, stream>>>(x, W1T, b1, dinv, hs_bf, N);
    // agg1 = bf16(dinv * (sum w*hs[s] + hs))
    aggregate_bf16<<<nbW, 256, 0, stream>>>(hs_bf, offs, ce, dinv, agg1_bf, N);
    // pes,qes = dinv * (relu(agg1@Wc + bc) @ [wmp,wmq])
    gemm2_stream<<<nb16, 64, 0, stream>>>(agg1_bf, WcT, bc, wmp, wmq, dinv, pe, qe, N);
    // p,q
    agg_scalar<<<nbN, 256, 0, stream>>>(pe, qe, offs, ce, dinv, bpq, p, q, N);
    // out
    edge_out_kernel<<<nbE, 256, 0, stream>>>(src, dst, p, q, bl, out, E);
}